// Round 1
// baseline (637.051 us; speedup 1.0000x reference)
//
#include <hip/hip_runtime.h>
#include <hip/hip_bf16.h>
#include <cstdint>
#include <cstddef>

typedef unsigned short u16;
typedef __attribute__((ext_vector_type(4))) unsigned short u16x4;
typedef __attribute__((ext_vector_type(8))) unsigned short u16x8;
typedef __attribute__((ext_vector_type(8))) short bf16x8;
typedef __attribute__((ext_vector_type(4))) float f32x4;

#define BB 8
#define NN 4096
#define CC 768
#define HH 12
#define DD 64
#define NHEADS 96           // B*H
#define QKVSZ 25165824LL    // 96*4096*64 elements per q/k/v plane

__device__ inline float b2f(u16 u) { return __uint_as_float(((unsigned)u) << 16); }
__device__ inline u16 f2b(float f) {
    unsigned u = __float_as_uint(f);
    return (u16)((u + 0x7fffu + ((u >> 16) & 1u)) >> 16);
}
__device__ inline f32x4 zero4() { f32x4 z = {0.f, 0.f, 0.f, 0.f}; return z; }

// ---------------------------------------------------------------- cast f32->bf16
__global__ void cast_f32_bf16(const float* __restrict__ src, u16* __restrict__ dst, int n) {
    long i0 = (long)(blockIdx.x * blockDim.x + threadIdx.x) * 4;
    long stride = (long)gridDim.x * blockDim.x * 4;
    for (long j = i0; j < n; j += stride) {
        float4 v = *(const float4*)(src + j);
        u16x4 o;
        o[0] = f2b(v.x); o[1] = f2b(v.y); o[2] = f2b(v.z); o[3] = f2b(v.w);
        *(u16x4*)(dst + j) = o;
    }
}

// ---------------------------------------------------------------- 128x128 bf16 GEMM (B^T form)
// Y[r,c] = sum_j A[r,j] * Bm[c,j].  K = 768 fixed.
// MODE 0: scatter-store qkv as bf16 into [3][B][H][N][64]
// MODE 1: add bias, store fp32 row-major [M][768]
template <int MODE>
__global__ __launch_bounds__(256) void gemm128(const u16* __restrict__ A, const u16* __restrict__ Bm,
                                               const float* __restrict__ bias, void* __restrict__ out) {
    constexpr int K = 768;
    __shared__ __align__(16) u16 lA[128 * 64];
    __shared__ __align__(16) u16 lB[128 * 64];
    const int tid = threadIdx.x;
    const int row0 = blockIdx.x * 128;
    const int col0 = blockIdx.y * 128;
    const int lane = tid & 63, wid = tid >> 6;
    const int wr = wid >> 1, wc = wid & 1;
    const int sr = tid >> 3, sc = (tid & 7) * 8;

    f32x4 acc[4][4];
#pragma unroll
    for (int i = 0; i < 4; ++i)
#pragma unroll
        for (int j = 0; j < 4; ++j) acc[i][j] = zero4();

    for (int kt = 0; kt < K; kt += 64) {
#pragma unroll
        for (int p = 0; p < 4; ++p) {
            int r = sr + p * 32;
            *(u16x8*)((char*)lA + ((r * 128 + sc * 2) ^ ((r & 7) << 4))) =
                *(const u16x8*)(A + (size_t)(row0 + r) * K + kt + sc);
            *(u16x8*)((char*)lB + ((r * 128 + sc * 2) ^ ((r & 7) << 4))) =
                *(const u16x8*)(Bm + (size_t)(col0 + r) * K + kt + sc);
        }
        __syncthreads();
#pragma unroll
        for (int kk = 0; kk < 64; kk += 32) {
            int kc = kk * 2 + ((lane >> 4) << 4);
            bf16x8 af[4], bf_[4];
#pragma unroll
            for (int i = 0; i < 4; ++i) {
                int ra = wr * 64 + i * 16 + (lane & 15);
                af[i] = *(const bf16x8*)((char*)lA + ((ra * 128 + kc) ^ ((ra & 7) << 4)));
                int rb = wc * 64 + i * 16 + (lane & 15);
                bf_[i] = *(const bf16x8*)((char*)lB + ((rb * 128 + kc) ^ ((rb & 7) << 4)));
            }
#pragma unroll
            for (int i = 0; i < 4; ++i)
#pragma unroll
                for (int j = 0; j < 4; ++j)
                    acc[i][j] = __builtin_amdgcn_mfma_f32_16x16x32_bf16(af[i], bf_[j], acc[i][j], 0, 0, 0);
        }
        __syncthreads();
    }

    const int g = lane >> 4, li = lane & 15;
#pragma unroll
    for (int i = 0; i < 4; ++i) {
#pragma unroll
        for (int j = 0; j < 4; ++j) {
            int c = col0 + wc * 64 + j * 16 + li;
            if constexpr (MODE == 0) {
                int part = c / 768, rem = c % 768;
                int h = rem >> 6, dd = rem & 63;
#pragma unroll
                for (int e = 0; e < 4; ++e) {
                    int r = row0 + wr * 64 + i * 16 + g * 4 + e;
                    int b = r >> 12, n = r & 4095;
                    ((u16*)out)[(((size_t)part * NHEADS + b * HH + h) * NN + n) * DD + dd] =
                        f2b(acc[i][j][e]);
                }
            } else {
                float bb = bias[c];
#pragma unroll
                for (int e = 0; e < 4; ++e) {
                    int r = row0 + wr * 64 + i * 16 + g * 4 + e;
                    ((float*)out)[(size_t)r * 768 + c] = acc[i][j][e] + bb;
                }
            }
        }
    }
}

// ---------------------------------------------------------------- per-head: gate, kq, softmax, fold
// One block per head (96 blocks, 256 threads).
__global__ __launch_bounds__(256) void head_kernel(
    const u16* __restrict__ qkv,
    const float* __restrict__ conv_w, const float* __restrict__ conv_b,
    const float* __restrict__ fc_w, const float* __restrict__ fc_b,
    const float* __restrict__ dw1_w, const float* __restrict__ dw1_b,
    const float* __restrict__ dw2_w, const float* __restrict__ dw2_b,
    u16* __restrict__ eff, float* __restrict__ effb) {
    const int head = blockIdx.x;
    const int tid = threadIdx.x;
    const int lane = tid & 63, wid = tid >> 6;

    __shared__ float sred[1024];
    __shared__ float smean[64];
    __shared__ float sgate[64];
    __shared__ __align__(16) u16 ktile[32 * 64];
    __shared__ __align__(16) u16 qtile[32 * 64];
    __shared__ float skq[64 * 64];
    __shared__ float sa[64 * 64];

    const u16* qh = qkv + (size_t)head * NN * DD;
    const u16* kh = qkv + QKVSZ + (size_t)head * NN * DD;
    const u16* vh = qkv + 2 * QKVSZ + (size_t)head * NN * DD;

    // ---- Phase A: mean of v over tokens, then gate = sigmoid(center-tap conv)
    {
        int rg = tid >> 4, cg = tid & 15;  // 16 row-groups x 16 col-groups(4 cols)
        float s0 = 0.f, s1 = 0.f, s2 = 0.f, s3 = 0.f;
        for (int n = rg; n < NN; n += 16) {
            u16x4 v = *(const u16x4*)(vh + (size_t)n * DD + cg * 4);
            s0 += b2f(v[0]); s1 += b2f(v[1]); s2 += b2f(v[2]); s3 += b2f(v[3]);
        }
        sred[rg * 64 + cg * 4 + 0] = s0;
        sred[rg * 64 + cg * 4 + 1] = s1;
        sred[rg * 64 + cg * 4 + 2] = s2;
        sred[rg * 64 + cg * 4 + 3] = s3;
    }
    __syncthreads();
    if (tid < 64) {
        float s = 0.f;
        for (int rg = 0; rg < 16; ++rg) s += sred[rg * 64 + tid];
        smean[tid] = s * (1.f / 4096.f);
    }
    __syncthreads();
    if (tid < 64) {
        float gsum = conv_b[tid];
        for (int i = 0; i < 64; ++i) gsum += conv_w[(tid * 64 + i) * 5 + 2] * smean[i];
        sgate[tid] = 1.f / (1.f + __expf(-gsum));
    }

    // ---- Phase B: kq[dd][e] = scale * sum_n k[n,dd]*q[n,e]  via MFMA
    f32x4 acc4[4];
#pragma unroll
    for (int i = 0; i < 4; ++i) acc4[i] = zero4();
    for (int n0 = 0; n0 < NN; n0 += 32) {
        int r = tid >> 3, c8 = (tid & 7) * 8;
        *(u16x8*)(ktile + r * 64 + c8) = *(const u16x8*)(kh + (size_t)(n0 + r) * DD + c8);
        *(u16x8*)(qtile + r * 64 + c8) = *(const u16x8*)(qh + (size_t)(n0 + r) * DD + c8);
        __syncthreads();
        int g8 = (lane >> 4) * 8, li = lane & 15;
        bf16x8 afr;
#pragma unroll
        for (int j = 0; j < 8; ++j) afr[j] = (short)ktile[(g8 + j) * 64 + wid * 16 + li];
#pragma unroll
        for (int ni = 0; ni < 4; ++ni) {
            bf16x8 bfr;
#pragma unroll
            for (int j = 0; j < 8; ++j) bfr[j] = (short)qtile[(g8 + j) * 64 + ni * 16 + li];
            acc4[ni] = __builtin_amdgcn_mfma_f32_16x16x32_bf16(afr, bfr, acc4[ni], 0, 0, 0);
        }
        __syncthreads();
    }
    {
        const float scale = 0.125f;  // 64^-0.5
        int g = lane >> 4, li = lane & 15;
#pragma unroll
        for (int ni = 0; ni < 4; ++ni)
#pragma unroll
            for (int e = 0; e < 4; ++e)
                skq[(wid * 16 + g * 4 + e) * 64 + ni * 16 + li] = acc4[ni][e] * scale;
    }
    __syncthreads();

    // ---- Phase C: a = relu(kq)@fc^T + fc_b; logits = a + kq; row softmax
    {
        int rr = tid >> 2, cg = (tid & 3) * 16;
        for (int c = cg; c < cg + 16; ++c) {
            float s = fc_b[c];
            for (int e = 0; e < 64; ++e) s += fmaxf(skq[rr * 64 + e], 0.f) * fc_w[c * 64 + e];
            sa[rr * 64 + c] = s + skq[rr * 64 + c];
        }
    }
    __syncthreads();
    if (tid < 64) {
        float m = -1e30f;
        for (int e = 0; e < 64; ++e) m = fmaxf(m, sa[tid * 64 + e]);
        float s = 0.f;
        for (int e = 0; e < 64; ++e) {
            float p = __expf(sa[tid * 64 + e] - m);
            sa[tid * 64 + e] = p;
            s += p;
        }
        float inv = 1.f / s;
        for (int e = 0; e < 64; ++e) sa[tid * 64 + e] *= inv;
    }
    __syncthreads();

    // ---- Phase D: fold a, dw-weights, gate into eff[o][tap*64+i] (bf16), effb[o]
    {
        int o = tid & 63, ig = tid >> 6;
        float gt = sgate[o];
        for (int i = ig * 16; i < ig * 16 + 16; ++i) {
            float t0 = 0.f, t1 = 0.f, t2 = 0.f, t3 = 0.f, t4 = 0.f;
            for (int e = 0; e < 64; ++e) {
                float a = sa[o * 64 + e];
                const float* w2 = dw2_w + ((size_t)(e * 64 + i)) * 5;
                t0 += a * w2[0]; t1 += a * w2[1]; t2 += a * w2[2]; t3 += a * w2[3]; t4 += a * w2[4];
                const float* w1 = dw1_w + ((size_t)(e * 64 + i)) * 3;
                t1 += a * w1[0]; t2 += a * w1[1]; t3 += a * w1[2];
            }
            u16* eo = eff + ((size_t)head * 64 + o) * 320 + i;
            eo[0]   = f2b(gt * t0);
            eo[64]  = f2b(gt * t1);
            eo[128] = f2b(gt * t2);
            eo[192] = f2b(gt * t3);
            eo[256] = f2b(gt * t4);
        }
        if (tid < 64) {
            float s = 0.f;
            for (int e = 0; e < 64; ++e) s += sa[tid * 64 + e] * (dw1_b[e] + dw2_b[e]);
            effb[head * 64 + tid] = sgate[tid] * s;
        }
    }
}

// ---------------------------------------------------------------- fused conv+attend+gate -> attn (bf16)
// out[n,o] = effb[o] + sum_{tap,i} eff[o][tap*64+i] * v[n+tap-2][i]  (zero-padded)
// grid: (32 n-tiles, 96 heads), 256 threads (4 waves x 32 rows each)
__global__ __launch_bounds__(256) void conv_attn(const u16* __restrict__ qkv, const u16* __restrict__ eff,
                                                 const float* __restrict__ effb, u16* __restrict__ attn) {
    const int nt = blockIdx.x, head = blockIdx.y;
    const int tid = threadIdx.x, lane = tid & 63, wid = tid >> 6;
    __shared__ __align__(16) u16 vt[132 * 64];
    const int n0 = nt * 128;
    const u16* vh = qkv + 2 * QKVSZ + (size_t)head * NN * DD;

    {
        int sr = tid >> 3, sc = (tid & 7) * 8;
#pragma unroll
        for (int p = 0; p < 5; ++p) {
            int r = sr + p * 32;
            if (r < 132) {
                int n = n0 - 2 + r;
                u16x8 v = {0, 0, 0, 0, 0, 0, 0, 0};
                if (n >= 0 && n < NN) v = *(const u16x8*)(vh + (size_t)n * DD + sc);
                *(u16x8*)((char*)vt + ((r * 128 + sc * 2) ^ ((r & 7) << 4))) = v;
            }
        }
    }
    __syncthreads();

    f32x4 acc[2][4];
#pragma unroll
    for (int s = 0; s < 2; ++s)
#pragma unroll
        for (int j = 0; j < 4; ++j) acc[s][j] = zero4();

    const u16* effh = eff + (size_t)head * 64 * 320;
    const int li = lane & 15, g = lane >> 4;
#pragma unroll
    for (int s = 0; s < 10; ++s) {
        int tap = s >> 1, half = s & 1;
        bf16x8 bfr[4];
#pragma unroll
        for (int nj = 0; nj < 4; ++nj)
            bfr[nj] = *(const bf16x8*)(effh + (size_t)(nj * 16 + li) * 320 + s * 32 + g * 8);
        int kc = half * 64 + g * 16;
#pragma unroll
        for (int sub = 0; sub < 2; ++sub) {
            int rr = wid * 32 + sub * 16 + li + tap;
            bf16x8 afr = *(const bf16x8*)((char*)vt + ((rr * 128 + kc) ^ ((rr & 7) << 4)));
#pragma unroll
            for (int nj = 0; nj < 4; ++nj)
                acc[sub][nj] = __builtin_amdgcn_mfma_f32_16x16x32_bf16(afr, bfr[nj], acc[sub][nj], 0, 0, 0);
        }
    }

    const int b = head / HH, h = head % HH;
#pragma unroll
    for (int sub = 0; sub < 2; ++sub)
#pragma unroll
        for (int nj = 0; nj < 4; ++nj) {
            int o = nj * 16 + li;
            float bb = effb[head * 64 + o];
#pragma unroll
            for (int e = 0; e < 4; ++e) {
                int m = wid * 32 + sub * 16 + g * 4 + e;
                size_t n = (size_t)n0 + m;
                attn[((size_t)b * NN + n) * CC + h * DD + o] = f2b(acc[sub][nj][e] + bb);
            }
        }
}

// ---------------------------------------------------------------- launch
extern "C" void kernel_launch(void* const* d_in, const int* in_sizes, int n_in,
                              void* d_out, int out_size, void* d_ws, size_t ws_size,
                              hipStream_t stream) {
    const float* x      = (const float*)d_in[0];
    const float* qkv_w  = (const float*)d_in[1];
    const float* proj_w = (const float*)d_in[2];
    const float* proj_b = (const float*)d_in[3];
    const float* conv_w = (const float*)d_in[4];
    const float* conv_b = (const float*)d_in[5];
    const float* fc_w   = (const float*)d_in[6];
    const float* fc_b   = (const float*)d_in[7];
    const float* dw1_w  = (const float*)d_in[8];
    const float* dw1_b  = (const float*)d_in[9];
    const float* dw2_w  = (const float*)d_in[10];
    const float* dw2_b  = (const float*)d_in[11];

    char* ws = (char*)d_ws;
    u16* xb    = (u16*)(ws);                       // 50,331,648 B
    u16* wqkv  = (u16*)(ws + 50331648);            //  3,538,944 B
    u16* wproj = (u16*)(ws + 53870592);            //  1,179,648 B
    u16* qkv   = (u16*)(ws + 55050240);            // 150,994,944 B
    u16* eff   = (u16*)(ws + 206045184);           //  3,932,160 B
    float* effb = (float*)(ws + 209977344);        //     24,576 B
    u16* attn  = (u16*)(ws + 210001920);           // 50,331,648 B  (total 260,333,568)
    float* out = (float*)d_out;

    cast_f32_bf16<<<1024, 256, 0, stream>>>(x, xb, BB * NN * CC);
    cast_f32_bf16<<<256, 256, 0, stream>>>(qkv_w, wqkv, 3 * CC * CC);
    cast_f32_bf16<<<256, 256, 0, stream>>>(proj_w, wproj, CC * CC);

    gemm128<0><<<dim3(256, 18), 256, 0, stream>>>(xb, wqkv, nullptr, qkv);

    head_kernel<<<96, 256, 0, stream>>>(qkv, conv_w, conv_b, fc_w, fc_b,
                                        dw1_w, dw1_b, dw2_w, dw2_b, eff, effb);

    conv_attn<<<dim3(32, 96), 256, 0, stream>>>(qkv, eff, effb, attn);

    gemm128<1><<<dim3(256, 6), 256, 0, stream>>>(attn, wproj, proj_b, out);
}

// Round 2
// 418.326 us; speedup vs baseline: 1.5229x; 1.5229x over previous
//
#include <hip/hip_runtime.h>
#include <hip/hip_bf16.h>
#include <cstdint>
#include <cstddef>

typedef unsigned short u16;
typedef __attribute__((ext_vector_type(4))) unsigned short u16x4;
typedef __attribute__((ext_vector_type(8))) unsigned short u16x8;
typedef __attribute__((ext_vector_type(8))) short bf16x8;
typedef __attribute__((ext_vector_type(4))) float f32x4;

#define BB 8
#define NN 4096
#define CC 768
#define HH 12
#define DD 64
#define NHEADS 96           // B*H
#define QKVSZ 25165824LL    // 96*4096*64 elements per q/k/v plane

__device__ inline float b2f(u16 u) { return __uint_as_float(((unsigned)u) << 16); }
__device__ inline u16 f2b(float f) {
    unsigned u = __float_as_uint(f);
    return (u16)((u + 0x7fffu + ((u >> 16) & 1u)) >> 16);
}
__device__ inline f32x4 zero4() { f32x4 z = {0.f, 0.f, 0.f, 0.f}; return z; }

// ---------------------------------------------------------------- cast f32->bf16
__global__ void cast_f32_bf16(const float* __restrict__ src, u16* __restrict__ dst, int n) {
    long i0 = (long)(blockIdx.x * blockDim.x + threadIdx.x) * 4;
    long stride = (long)gridDim.x * blockDim.x * 4;
    for (long j = i0; j < n; j += stride) {
        float4 v = *(const float4*)(src + j);
        u16x4 o;
        o[0] = f2b(v.x); o[1] = f2b(v.y); o[2] = f2b(v.z); o[3] = f2b(v.w);
        *(u16x4*)(dst + j) = o;
    }
}

// ---------------------------------------------------------------- 128x128 bf16 GEMM (B^T form)
// Y[r,c] = sum_j A[r,j] * Bm[c,j].  K = 768 fixed.
// MODE 0: scatter-store qkv as bf16 into [3][B][H][N][64]
// MODE 1: add bias, store fp32 row-major [M][768]
template <int MODE>
__global__ __launch_bounds__(256) void gemm128(const u16* __restrict__ A, const u16* __restrict__ Bm,
                                               const float* __restrict__ bias, void* __restrict__ out) {
    constexpr int K = 768;
    __shared__ __align__(16) u16 lA[128 * 64];
    __shared__ __align__(16) u16 lB[128 * 64];
    const int tid = threadIdx.x;
    const int row0 = blockIdx.x * 128;
    const int col0 = blockIdx.y * 128;
    const int lane = tid & 63, wid = tid >> 6;
    const int wr = wid >> 1, wc = wid & 1;
    const int sr = tid >> 3, sc = (tid & 7) * 8;

    f32x4 acc[4][4];
#pragma unroll
    for (int i = 0; i < 4; ++i)
#pragma unroll
        for (int j = 0; j < 4; ++j) acc[i][j] = zero4();

    for (int kt = 0; kt < K; kt += 64) {
#pragma unroll
        for (int p = 0; p < 4; ++p) {
            int r = sr + p * 32;
            *(u16x8*)((char*)lA + ((r * 128 + sc * 2) ^ ((r & 7) << 4))) =
                *(const u16x8*)(A + (size_t)(row0 + r) * K + kt + sc);
            *(u16x8*)((char*)lB + ((r * 128 + sc * 2) ^ ((r & 7) << 4))) =
                *(const u16x8*)(Bm + (size_t)(col0 + r) * K + kt + sc);
        }
        __syncthreads();
#pragma unroll
        for (int kk = 0; kk < 64; kk += 32) {
            int kc = kk * 2 + ((lane >> 4) << 4);
            bf16x8 af[4], bf_[4];
#pragma unroll
            for (int i = 0; i < 4; ++i) {
                int ra = wr * 64 + i * 16 + (lane & 15);
                af[i] = *(const bf16x8*)((char*)lA + ((ra * 128 + kc) ^ ((ra & 7) << 4)));
                int rb = wc * 64 + i * 16 + (lane & 15);
                bf_[i] = *(const bf16x8*)((char*)lB + ((rb * 128 + kc) ^ ((rb & 7) << 4)));
            }
#pragma unroll
            for (int i = 0; i < 4; ++i)
#pragma unroll
                for (int j = 0; j < 4; ++j)
                    acc[i][j] = __builtin_amdgcn_mfma_f32_16x16x32_bf16(af[i], bf_[j], acc[i][j], 0, 0, 0);
        }
        __syncthreads();
    }

    const int g = lane >> 4, li = lane & 15;
#pragma unroll
    for (int i = 0; i < 4; ++i) {
#pragma unroll
        for (int j = 0; j < 4; ++j) {
            int c = col0 + wc * 64 + j * 16 + li;
            if constexpr (MODE == 0) {
                int part = c / 768, rem = c % 768;
                int h = rem >> 6, dd = rem & 63;
#pragma unroll
                for (int e = 0; e < 4; ++e) {
                    int r = row0 + wr * 64 + i * 16 + g * 4 + e;
                    int b = r >> 12, n = r & 4095;
                    ((u16*)out)[(((size_t)part * NHEADS + b * HH + h) * NN + n) * DD + dd] =
                        f2b(acc[i][j][e]);
                }
            } else {
                float bb = bias[c];
#pragma unroll
                for (int e = 0; e < 4; ++e) {
                    int r = row0 + wr * 64 + i * 16 + g * 4 + e;
                    ((float*)out)[(size_t)r * 768 + c] = acc[i][j][e] + bb;
                }
            }
        }
    }
}

// ---------------------------------------------------------------- K1: partial sums of v over tokens
// grid (96, 16): block sums 256 tokens -> meanp[head][chunk][64] (raw sums)
__global__ __launch_bounds__(256) void mean_partial(const u16* __restrict__ qkv, float* __restrict__ meanp) {
    const int head = blockIdx.x, c = blockIdx.y;
    const int tid = threadIdx.x;
    const u16* vh = qkv + 2 * QKVSZ + (size_t)head * NN * DD;
    __shared__ float sred[16 * 64];
    int rg = tid >> 4, cg = tid & 15;
    int n0 = c * 256;
    float s0 = 0.f, s1 = 0.f, s2 = 0.f, s3 = 0.f;
#pragma unroll 4
    for (int it = 0; it < 16; ++it) {
        int n = n0 + rg + it * 16;
        u16x4 v = *(const u16x4*)(vh + (size_t)n * DD + cg * 4);
        s0 += b2f(v[0]); s1 += b2f(v[1]); s2 += b2f(v[2]); s3 += b2f(v[3]);
    }
    sred[rg * 64 + cg * 4 + 0] = s0;
    sred[rg * 64 + cg * 4 + 1] = s1;
    sred[rg * 64 + cg * 4 + 2] = s2;
    sred[rg * 64 + cg * 4 + 3] = s3;
    __syncthreads();
    if (tid < 64) {
        float s = 0.f;
#pragma unroll
        for (int rg2 = 0; rg2 < 16; ++rg2) s += sred[rg2 * 64 + tid];
        meanp[((size_t)head * 16 + c) * 64 + tid] = s;
    }
}

// ---------------------------------------------------------------- K2: split-K kq partials via MFMA
// grid (96, 4), 4 waves. Each wave: private 256-token chunk, private LDS tiles, NO barriers.
// kqp[head][slot=part*4+wid][dd][e] = sum_n k[n,dd]*q[n,e]  (unscaled)
__global__ __launch_bounds__(256) void kq_partial(const u16* __restrict__ qkv, float* __restrict__ kqp) {
    const int head = blockIdx.x, part = blockIdx.y;
    const int tid = threadIdx.x, lane = tid & 63, wid = tid >> 6;
    __shared__ __align__(16) u16 tiles[4][2][32 * 64];
    u16* kt = tiles[wid][0];
    u16* qt = tiles[wid][1];
    const u16* qh = qkv + (size_t)head * NN * DD;
    const u16* kh = qkv + QKVSZ + (size_t)head * NN * DD;
    const int nbase = part * 1024 + wid * 256;

    f32x4 acc[4][4];
#pragma unroll
    for (int i = 0; i < 4; ++i)
#pragma unroll
        for (int j = 0; j < 4; ++j) acc[i][j] = zero4();

    const int srow = lane >> 3, schunk = (lane & 7) * 8;
    const int g8 = (lane >> 4) * 8, li = lane & 15;

    for (int it = 0; it < 8; ++it) {
        int n0 = nbase + it * 32;
#pragma unroll
        for (int p = 0; p < 4; ++p) {
            int r = srow + p * 8;
            *(u16x8*)(kt + r * 64 + schunk) = *(const u16x8*)(kh + (size_t)(n0 + r) * DD + schunk);
            *(u16x8*)(qt + r * 64 + schunk) = *(const u16x8*)(qh + (size_t)(n0 + r) * DD + schunk);
        }
        bf16x8 af[4], bf_[4];
#pragma unroll
        for (int i = 0; i < 4; ++i)
#pragma unroll
            for (int j = 0; j < 8; ++j) af[i][j] = (short)kt[(g8 + j) * 64 + i * 16 + li];
#pragma unroll
        for (int i = 0; i < 4; ++i)
#pragma unroll
            for (int j = 0; j < 8; ++j) bf_[i][j] = (short)qt[(g8 + j) * 64 + i * 16 + li];
#pragma unroll
        for (int i = 0; i < 4; ++i)
#pragma unroll
            for (int j = 0; j < 4; ++j)
                acc[i][j] = __builtin_amdgcn_mfma_f32_16x16x32_bf16(af[i], bf_[j], acc[i][j], 0, 0, 0);
    }

    const int slot = part * 4 + wid;
    const int g = lane >> 4;
    float* dst = kqp + ((size_t)head * 16 + slot) * 4096;
#pragma unroll
    for (int i = 0; i < 4; ++i)
#pragma unroll
        for (int j = 0; j < 4; ++j)
#pragma unroll
            for (int e = 0; e < 4; ++e)
                dst[(i * 16 + g * 4 + e) * 64 + j * 16 + li] = acc[i][j][e];
}

// ---------------------------------------------------------------- K3: reduce partials, gate, fc+softmax
// 96 blocks. Writes sa_g[head][o][e] (softmax probs), gate_g[head][o], effb[head][o].
__global__ __launch_bounds__(256) void head_finish(
    const float* __restrict__ kqp, const float* __restrict__ meanp,
    const float* __restrict__ conv_w, const float* __restrict__ conv_b,
    const float* __restrict__ fc_w, const float* __restrict__ fc_b,
    const float* __restrict__ dw1_b, const float* __restrict__ dw2_b,
    float* __restrict__ sa_g, float* __restrict__ gate_g, float* __restrict__ effb) {
    const int head = blockIdx.x;
    const int tid = threadIdx.x;
    __shared__ float skq[64 * 64];
    __shared__ float sa[64 * 64];
    __shared__ float smean[64];
    __shared__ float sgate[64];

    // reduce kq partials (x0.125 scale)
    for (int idx = tid; idx < 4096; idx += 256) {
        float s = 0.f;
#pragma unroll
        for (int p = 0; p < 16; ++p) s += kqp[((size_t)head * 16 + p) * 4096 + idx];
        skq[idx] = s * 0.125f;
    }
    if (tid < 64) {
        float s = 0.f;
#pragma unroll
        for (int p = 0; p < 16; ++p) s += meanp[((size_t)head * 16 + p) * 64 + tid];
        smean[tid] = s * (1.f / 4096.f);
    }
    __syncthreads();
    if (tid < 64) {
        float gsum = conv_b[tid];
        for (int i = 0; i < 64; ++i) gsum += conv_w[(tid * 64 + i) * 5 + 2] * smean[i];
        float gt = 1.f / (1.f + __expf(-gsum));
        sgate[tid] = gt;
        gate_g[head * 64 + tid] = gt;
    }

    // a = relu(kq)@fc^T + fc_b; logits = a + kq
    {
        int rr = tid >> 2, cg = (tid & 3) * 16;
        for (int c = cg; c < cg + 16; ++c) {
            float s = fc_b[c];
            for (int e = 0; e < 64; ++e) s += fmaxf(skq[rr * 64 + e], 0.f) * fc_w[c * 64 + e];
            sa[rr * 64 + c] = s + skq[rr * 64 + c];
        }
    }
    __syncthreads();
    if (tid < 64) {
        float m = -1e30f;
        for (int e = 0; e < 64; ++e) m = fmaxf(m, sa[tid * 64 + e]);
        float s = 0.f;
        for (int e = 0; e < 64; ++e) {
            float p = __expf(sa[tid * 64 + e] - m);
            sa[tid * 64 + e] = p;
            s += p;
        }
        float inv = 1.f / s;
        for (int e = 0; e < 64; ++e) sa[tid * 64 + e] *= inv;
    }
    __syncthreads();
    for (int idx = tid; idx < 4096; idx += 256) sa_g[(size_t)head * 4096 + idx] = sa[idx];
    if (tid < 64) {
        float s = 0.f;
        for (int e = 0; e < 64; ++e) s += sa[tid * 64 + e] * (dw1_b[e] + dw2_b[e]);
        effb[head * 64 + tid] = sgate[tid] * s;
    }
}

// ---------------------------------------------------------------- K4: fold a,gate,dw -> eff (bf16)
// grid (96,4): block handles 16 i's. thread: il=tid&15 (i), og=tid>>4 (4 o's each).
__global__ __launch_bounds__(256) void fold_eff(
    const float* __restrict__ sa_g, const float* __restrict__ gate_g,
    const float* __restrict__ dw1_w, const float* __restrict__ dw2_w,
    u16* __restrict__ eff) {
    const int head = blockIdx.x, ig = blockIdx.y;
    const int tid = threadIdx.x;
    __shared__ float ssa[4096];
    __shared__ float sw2[64 * 16 * 5];
    __shared__ float sw1[64 * 16 * 3];

    for (int idx = tid; idx < 4096; idx += 256) ssa[idx] = sa_g[(size_t)head * 4096 + idx];
    for (int idx = tid; idx < 64 * 16 * 5; idx += 256) {
        int e = idx / 80, rem = idx % 80, il = rem / 5, t = rem % 5;
        sw2[idx] = dw2_w[((size_t)(e * 64 + ig * 16 + il)) * 5 + t];
    }
    for (int idx = tid; idx < 64 * 16 * 3; idx += 256) {
        int e = idx / 48, rem = idx % 48, il = rem / 3, t = rem % 3;
        sw1[idx] = dw1_w[((size_t)(e * 64 + ig * 16 + il)) * 3 + t];
    }
    __syncthreads();

    const int il = tid & 15, og = tid >> 4;
    const int i = ig * 16 + il;
    float t[4][5];
#pragma unroll
    for (int o = 0; o < 4; ++o)
#pragma unroll
        for (int tp = 0; tp < 5; ++tp) t[o][tp] = 0.f;

    for (int e = 0; e < 64; ++e) {
        float a0 = ssa[(og * 4 + 0) * 64 + e];
        float a1 = ssa[(og * 4 + 1) * 64 + e];
        float a2 = ssa[(og * 4 + 2) * 64 + e];
        float a3 = ssa[(og * 4 + 3) * 64 + e];
        const float* w2 = sw2 + (e * 16 + il) * 5;
        const float* w1 = sw1 + (e * 16 + il) * 3;
        float c0 = w2[0], c1 = w2[1] + w1[0], c2 = w2[2] + w1[1], c3 = w2[3] + w1[2], c4 = w2[4];
        t[0][0] += a0 * c0; t[0][1] += a0 * c1; t[0][2] += a0 * c2; t[0][3] += a0 * c3; t[0][4] += a0 * c4;
        t[1][0] += a1 * c0; t[1][1] += a1 * c1; t[1][2] += a1 * c2; t[1][3] += a1 * c3; t[1][4] += a1 * c4;
        t[2][0] += a2 * c0; t[2][1] += a2 * c1; t[2][2] += a2 * c2; t[2][3] += a2 * c3; t[2][4] += a2 * c4;
        t[3][0] += a3 * c0; t[3][1] += a3 * c1; t[3][2] += a3 * c2; t[3][3] += a3 * c3; t[3][4] += a3 * c4;
    }
#pragma unroll
    for (int o = 0; o < 4; ++o) {
        int oo = og * 4 + o;
        float gt = gate_g[head * 64 + oo];
        u16* eo = eff + ((size_t)head * 64 + oo) * 320 + i;
#pragma unroll
        for (int tp = 0; tp < 5; ++tp) eo[tp * 64] = f2b(gt * t[o][tp]);
    }
}

// ---------------------------------------------------------------- fused conv+attend+gate -> attn (bf16)
// out[n,o] = effb[o] + sum_{tap,i} eff[o][tap*64+i] * v[n+tap-2][i]  (zero-padded)
// grid: (32 n-tiles, 96 heads), 256 threads (4 waves x 32 rows each)
__global__ __launch_bounds__(256) void conv_attn(const u16* __restrict__ qkv, const u16* __restrict__ eff,
                                                 const float* __restrict__ effb, u16* __restrict__ attn) {
    const int nt = blockIdx.x, head = blockIdx.y;
    const int tid = threadIdx.x, lane = tid & 63, wid = tid >> 6;
    __shared__ __align__(16) u16 vt[132 * 64];
    const int n0 = nt * 128;
    const u16* vh = qkv + 2 * QKVSZ + (size_t)head * NN * DD;

    {
        int sr = tid >> 3, sc = (tid & 7) * 8;
#pragma unroll
        for (int p = 0; p < 5; ++p) {
            int r = sr + p * 32;
            if (r < 132) {
                int n = n0 - 2 + r;
                u16x8 v = {0, 0, 0, 0, 0, 0, 0, 0};
                if (n >= 0 && n < NN) v = *(const u16x8*)(vh + (size_t)n * DD + sc);
                *(u16x8*)((char*)vt + ((r * 128 + sc * 2) ^ ((r & 7) << 4))) = v;
            }
        }
    }
    __syncthreads();

    f32x4 acc[2][4];
#pragma unroll
    for (int s = 0; s < 2; ++s)
#pragma unroll
        for (int j = 0; j < 4; ++j) acc[s][j] = zero4();

    const u16* effh = eff + (size_t)head * 64 * 320;
    const int li = lane & 15, g = lane >> 4;
#pragma unroll
    for (int s = 0; s < 10; ++s) {
        int tap = s >> 1, half = s & 1;
        bf16x8 bfr[4];
#pragma unroll
        for (int nj = 0; nj < 4; ++nj)
            bfr[nj] = *(const bf16x8*)(effh + (size_t)(nj * 16 + li) * 320 + s * 32 + g * 8);
        int kc = half * 64 + g * 16;
#pragma unroll
        for (int sub = 0; sub < 2; ++sub) {
            int rr = wid * 32 + sub * 16 + li + tap;
            bf16x8 afr = *(const bf16x8*)((char*)vt + ((rr * 128 + kc) ^ ((rr & 7) << 4)));
#pragma unroll
            for (int nj = 0; nj < 4; ++nj)
                acc[sub][nj] = __builtin_amdgcn_mfma_f32_16x16x32_bf16(afr, bfr[nj], acc[sub][nj], 0, 0, 0);
        }
    }

    const int b = head / HH, h = head % HH;
#pragma unroll
    for (int sub = 0; sub < 2; ++sub)
#pragma unroll
        for (int nj = 0; nj < 4; ++nj) {
            int o = nj * 16 + li;
            float bb = effb[head * 64 + o];
#pragma unroll
            for (int e = 0; e < 4; ++e) {
                int m = wid * 32 + sub * 16 + g * 4 + e;
                size_t n = (size_t)n0 + m;
                attn[((size_t)b * NN + n) * CC + h * DD + o] = f2b(acc[sub][nj][e] + bb);
            }
        }
}

// ---------------------------------------------------------------- launch
extern "C" void kernel_launch(void* const* d_in, const int* in_sizes, int n_in,
                              void* d_out, int out_size, void* d_ws, size_t ws_size,
                              hipStream_t stream) {
    const float* x      = (const float*)d_in[0];
    const float* qkv_w  = (const float*)d_in[1];
    const float* proj_w = (const float*)d_in[2];
    const float* proj_b = (const float*)d_in[3];
    const float* conv_w = (const float*)d_in[4];
    const float* conv_b = (const float*)d_in[5];
    const float* fc_w   = (const float*)d_in[6];
    const float* fc_b   = (const float*)d_in[7];
    const float* dw1_w  = (const float*)d_in[8];
    const float* dw1_b  = (const float*)d_in[9];
    const float* dw2_w  = (const float*)d_in[10];
    const float* dw2_b  = (const float*)d_in[11];

    char* ws = (char*)d_ws;
    u16* xb    = (u16*)(ws);                       // 50,331,648 B (dead after gemm<0>)
    u16* wqkv  = (u16*)(ws + 50331648);            //  3,538,944 B
    u16* wproj = (u16*)(ws + 53870592);            //  1,179,648 B
    u16* qkv   = (u16*)(ws + 55050240);            // 150,994,944 B
    u16* eff   = (u16*)(ws + 206045184);           //  3,932,160 B
    float* effb = (float*)(ws + 209977344);        //     24,576 B
    u16* attn  = (u16*)(ws + 210001920);           // 50,331,648 B

    // overlay into xb region (only used after gemm<0> has consumed xb)
    float* kqp   = (float*)(ws);                   // 25,165,824 B
    float* meanp = (float*)(ws + 25165824);        //    393,216 B
    float* sa_g  = (float*)(ws + 25559040);        //  1,572,864 B
    float* gate_g = (float*)(ws + 27131904);       //     24,576 B

    float* out = (float*)d_out;

    cast_f32_bf16<<<1024, 256, 0, stream>>>(x, xb, BB * NN * CC);
    cast_f32_bf16<<<256, 256, 0, stream>>>(qkv_w, wqkv, 3 * CC * CC);
    cast_f32_bf16<<<256, 256, 0, stream>>>(proj_w, wproj, CC * CC);

    gemm128<0><<<dim3(256, 18), 256, 0, stream>>>(xb, wqkv, nullptr, qkv);

    mean_partial<<<dim3(96, 16), 256, 0, stream>>>(qkv, meanp);
    kq_partial<<<dim3(96, 4), 256, 0, stream>>>(qkv, kqp);
    head_finish<<<96, 256, 0, stream>>>(kqp, meanp, conv_w, conv_b, fc_w, fc_b,
                                        dw1_b, dw2_b, sa_g, gate_g, effb);
    fold_eff<<<dim3(96, 4), 256, 0, stream>>>(sa_g, gate_g, dw1_w, dw2_w, eff);

    conv_attn<<<dim3(32, 96), 256, 0, stream>>>(qkv, eff, effb, attn);

    gemm128<1><<<dim3(256, 6), 256, 0, stream>>>(attn, wproj, proj_b, out);
}